// Round 1
// 422.029 us; speedup vs baseline: 1.6464x; 1.6464x over previous
//
#include <hip/hip_runtime.h>
#include <math.h>

#define LEN   2048
#define EDIM  512
#define NB    16
#define NH    8
#define HD    64
#define TOPK  7
#define TWN   2047   // sum of per-stage twiddle tables: 1024+512+...+1

__device__ inline float2 cmul(float2 a, float2 b) {
    return make_float2(a.x * b.x - a.y * b.y, a.x * b.y + a.y * b.x);
}

// K0: (B, L, E) -> (B*E, L) transpose for q and k. 32x32 tiles.
__global__ __launch_bounds__(256) void transpose_qk(const float* __restrict__ q,
                                                    const float* __restrict__ k,
                                                    float* __restrict__ qT,
                                                    float* __restrict__ kT) {
    __shared__ float tile[32][33];
    int b  = blockIdx.z;
    int e0 = blockIdx.x * 32;
    int t0 = blockIdx.y * 32;
    const float* qb = q + (size_t)b * LEN * EDIM;
    const float* kb = k + (size_t)b * LEN * EDIM;
    float* qTb = qT + (size_t)b * EDIM * LEN;
    float* kTb = kT + (size_t)b * EDIM * LEN;
    int x = threadIdx.x;   // 0..31
    int y = threadIdx.y;   // 0..7
    for (int r = 0; r < 32; r += 8)
        tile[y + r][x] = qb[(size_t)(t0 + y + r) * EDIM + e0 + x];
    __syncthreads();
    for (int r = 0; r < 32; r += 8)
        qTb[(size_t)(e0 + y + r) * LEN + t0 + x] = tile[x][y + r];
    __syncthreads();
    for (int r = 0; r < 32; r += 8)
        tile[y + r][x] = kb[(size_t)(t0 + y + r) * EDIM + e0 + x];
    __syncthreads();
    for (int r = 0; r < 32; r += 8)
        kTb[(size_t)(e0 + y + r) * LEN + t0 + x] = tile[x][y + r];
}

// Per-stage contiguous twiddle tables. Table k holds w_N^(t<<k) for
// t < 1024>>k at offset 2048 - (2048>>k). Stage reads are stride-1 in t
// -> conflict-free (the old TW[t<<s] was a 32-way bank conflict for s>=4).
__device__ inline void fill_tw(float2* TWS, int tid) {
    for (int k = 0; k <= 10; ++k) {
        int sz  = 1024 >> k;
        int off = 2048 - (2048 >> k);
        for (int t = tid; t < sz; t += 256) {
            float s, c;
            sincosf(-6.283185307179586f * (float)(t << k) / 2048.0f, &s, &c);
            TWS[off + t] = make_float2(c, s);
        }
    }
}

// Packed FFT correlation core.
// In:  A = q0 + i*k0 (time domain), Bs = q1 + i*k1 (two channels per block).
// Forward radix-2 DIF (natural -> bitrev) on both arrays; Hermitian unpack +
// Q*conj(K) per channel + repack W = C0 + i*C1 in bitrev domain; inverse DIT.
// Out: A[t] = (corr0[t], corr1[t]) * LEN (caller scales by 1/LEN).
__device__ inline void fft_corr_core2(float2* A, float2* Bs, const float2* TWS, int tid) {
    for (int s = 0; s < 11; ++s) {
        int m   = 1024 >> s;
        int off = 2048 - (2048 >> s);
        for (int j = tid; j < 1024; j += 256) {
            int t  = j & (m - 1);
            int i0 = ((j >> (10 - s)) << (11 - s)) + t;
            int i1 = i0 + m;
            float2 w = TWS[off + t];
            float2 a = A[i0], b = A[i1];
            A[i0] = make_float2(a.x + b.x, a.y + b.y);
            A[i1] = cmul(make_float2(a.x - b.x, a.y - b.y), w);
            a = Bs[i0]; b = Bs[i1];
            Bs[i0] = make_float2(a.x + b.x, a.y + b.y);
            Bs[i1] = cmul(make_float2(a.x - b.x, a.y - b.y), w);
        }
        __syncthreads();
    }
    // Pointwise in bitrev domain. Thread owning f also owns N-f: each LDS
    // element is read+written by exactly one thread -> no intra-phase races.
    for (int f = tid; f <= 1024; f += 256) {
        int nf = (2048 - f) & 2047;
        int ia = __brev((unsigned)f)  >> 21;   // 11-bit bit-reverse
        int ib = __brev((unsigned)nf) >> 21;
        float2 z1 = A[ia],  z1n = A[ib];
        float2 z2 = Bs[ia], z2n = Bs[ib];
        // ch0: Q = (z + conj(zn))/2 ; K = (z - conj(zn))/(2i); C = Q*conj(K)
        float Qx = 0.5f * (z1.x + z1n.x), Qy = 0.5f * (z1.y - z1n.y);
        float Kx = 0.5f * (z1.y + z1n.y), Ky = 0.5f * (z1n.x - z1.x);
        float C1x = Qx * Kx + Qy * Ky;
        float C1y = Qy * Kx - Qx * Ky;
        // ch1
        float Px = 0.5f * (z2.x + z2n.x), Py = 0.5f * (z2.y - z2n.y);
        float Lx = 0.5f * (z2.y + z2n.y), Ly = 0.5f * (z2n.x - z2.x);
        float C2x = Px * Lx + Py * Ly;
        float C2y = Py * Lx - Px * Ly;
        // W[f] = C1 + i*C2 ; W[N-f] = conj(C1) + i*conj(C2)
        A[ia] = make_float2(C1x - C2y, C1y + C2x);
        if (f != 0 && f != 1024)
            A[ib] = make_float2(C1x + C2y, C2x - C1y);
    }
    __syncthreads();
    for (int s = 0; s < 11; ++s) {
        int m   = 1 << s;
        int off = 2048 - (2048 >> (10 - s));
        for (int j = tid; j < 1024; j += 256) {
            int t  = j & (m - 1);
            int i0 = ((j >> s) << (s + 1)) + t;
            int i1 = i0 + m;
            float2 wc = TWS[off + t];
            float2 w  = make_float2(wc.x, -wc.y);   // conj for inverse
            float2 a  = A[i0];
            float2 b  = cmul(A[i1], w);
            A[i0] = make_float2(a.x + b.x, a.y + b.y);
            A[i1] = make_float2(a.x - b.x, a.y - b.y);
        }
        __syncthreads();
    }
}

// K1 (Path A): two contiguous channel rows per block (from transposed bufs).
// corr may alias qT: rows ch0,ch0+1 fully read into LDS before the store.
__global__ __launch_bounds__(256) void fft_corr(const float* qT,
                                                const float* kT,
                                                float* corr) {
    __shared__ float2 A[LEN];
    __shared__ float2 Bs[LEN];
    __shared__ float2 TWS[TWN];
    int ch0 = blockIdx.x * 2;
    int tid = threadIdx.x;
    const float* q0 = qT + (size_t)ch0 * LEN;
    const float* k0 = kT + (size_t)ch0 * LEN;
    fill_tw(TWS, tid);
    const float4* q4 = (const float4*)q0;
    const float4* k4 = (const float4*)k0;
    for (int t4 = tid; t4 < LEN / 4; t4 += 256) {
        float4 qa = q4[t4],           ka = k4[t4];
        float4 qb = q4[t4 + LEN / 4], kb = k4[t4 + LEN / 4];
        int t = t4 * 4;
        A[t]      = make_float2(qa.x, ka.x);
        A[t + 1]  = make_float2(qa.y, ka.y);
        A[t + 2]  = make_float2(qa.z, ka.z);
        A[t + 3]  = make_float2(qa.w, ka.w);
        Bs[t]     = make_float2(qb.x, kb.x);
        Bs[t + 1] = make_float2(qb.y, kb.y);
        Bs[t + 2] = make_float2(qb.z, kb.z);
        Bs[t + 3] = make_float2(qb.w, kb.w);
    }
    __syncthreads();
    fft_corr_core2(A, Bs, TWS, tid);
    const float inv = 1.0f / (float)LEN;
    float4* c0 = (float4*)(corr + (size_t)ch0 * LEN);
    float4* c1 = (float4*)(corr + (size_t)(ch0 + 1) * LEN);
    for (int t4 = tid; t4 < LEN / 4; t4 += 256) {
        int t = t4 * 4;
        c0[t4] = make_float4(A[t].x * inv, A[t + 1].x * inv,
                             A[t + 2].x * inv, A[t + 3].x * inv);
        c1[t4] = make_float4(A[t].y * inv, A[t + 1].y * inv,
                             A[t + 2].y * inv, A[t + 3].y * inv);
    }
}

// K1 (Path B): read q,k strided directly from (B,L,E); corr rows chunk-local.
__global__ __launch_bounds__(256) void fft_corr_strided(const float* q,
                                                        const float* k,
                                                        float* corr,
                                                        int chStart) {
    __shared__ float2 A[LEN];
    __shared__ float2 Bs[LEN];
    __shared__ float2 TWS[TWN];
    int chLocal = blockIdx.x * 2;
    int gch = chStart + chLocal;
    int b   = gch >> 9;           // / EDIM
    int e   = gch & (EDIM - 1);   // even (HD per head, paired)
    int tid = threadIdx.x;
    const float* qr = q + (size_t)b * LEN * EDIM + e;
    const float* kr = k + (size_t)b * LEN * EDIM + e;
    fill_tw(TWS, tid);
    for (int t = tid; t < LEN; t += 256) {
        float2 qv = *(const float2*)(qr + (size_t)t * EDIM);
        float2 kv = *(const float2*)(kr + (size_t)t * EDIM);
        A[t]  = make_float2(qv.x, kv.x);
        Bs[t] = make_float2(qv.y, kv.y);
    }
    __syncthreads();
    fft_corr_core2(A, Bs, TWS, tid);
    const float inv = 1.0f / (float)LEN;
    float4* c0 = (float4*)(corr + (size_t)chLocal * LEN);
    float4* c1 = (float4*)(corr + (size_t)(chLocal + 1) * LEN);
    for (int t4 = tid; t4 < LEN / 4; t4 += 256) {
        int t = t4 * 4;
        c0[t4] = make_float4(A[t].x * inv, A[t + 1].x * inv,
                             A[t + 2].x * inv, A[t + 3].x * inv);
        c1[t4] = make_float4(A[t].y * inv, A[t + 1].y * inv,
                             A[t + 2].y * inv, A[t + 3].y * inv);
    }
}

// K2: per (b,h,l): top-7 over 64 channel-scores, softmax, gather-weighted sum.
// Phase 1: one THREAD per l (256 l per block) scans its 64 scores serially
// with a branchless 7-deep insertion network -- no cross-lane ops (the old
// 7x6-level shfl_xor ladder was the VALU bottleneck: ~300 VALU + 84 DS wave
// insts per l). Loads are coalesced (lane <-> l).
// Phase 2: lane <-> channel; coalesced 256B value gathers (mostly L2-hits).
__global__ __launch_bounds__(256) void topk_agg(const float* __restrict__ corr,
                                                const float* __restrict__ values,
                                                float* __restrict__ out,
                                                int bhBase) {
    __shared__ float2 w_d[256][TOPK];   // (weight, bitcast delay) per local l
    int l0 = blockIdx.x * 256;
    int lh = blockIdx.y;            // local head index within chunk
    int bh = bhBase + lh;
    int b  = bh >> 3;
    int h  = bh & 7;
    int tid = threadIdx.x;

    // ---- phase 1: per-thread top-7 over the 64 channels of row l = l0+tid
    const float* cb = corr + (size_t)lh * HD * LEN + l0 + tid;
    float wk[TOPK];
    int   dk[TOPK];
    #pragma unroll
    for (int t = 0; t < TOPK; ++t) { wk[t] = -INFINITY; dk[t] = 0; }
    #pragma unroll 8
    for (int c = 0; c < HD; ++c) {
        float nv = cb[(size_t)c * LEN];
        int   nd = c;
        #pragma unroll
        for (int t = 0; t < TOPK; ++t) {   // stable: strict > keeps low index first
            bool  m  = nv > wk[t];
            float tv = wk[t]; int td = dk[t];
            wk[t] = m ? nv : tv;
            dk[t] = m ? nd : td;
            nv    = m ? tv : nv;
            nd    = m ? td : nd;
        }
    }
    float mx = wk[0], sum = 0.f;
    float e[TOPK];
    #pragma unroll
    for (int t = 0; t < TOPK; ++t) { e[t] = expf(wk[t] - mx); sum += e[t]; }
    float invs = 1.f / sum;
    #pragma unroll
    for (int t = 0; t < TOPK; ++t)
        w_d[tid][t] = make_float2(e[t] * invs, __int_as_float(dk[t]));
    __syncthreads();

    // ---- phase 2: gather. lane = channel, each wave covers 64 l.
    int lane = tid & 63;
    int wave = tid >> 6;
    const float* vb = values + (size_t)b * LEN * EDIM + h * HD + lane;
    float*       ob = out    + (size_t)b * LEN * EDIM + h * HD + lane;
    for (int i = 0; i < 64; ++i) {
        int lp = wave * 64 + i;
        int l  = l0 + lp;
        float acc = 0.f;
        #pragma unroll
        for (int t = 0; t < TOPK; ++t) {
            float2 wd = w_d[lp][t];     // wave-uniform -> LDS broadcast
            int idx = (l - __float_as_int(wd.y)) & (LEN - 1);
            acc += wd.x * vb[(size_t)idx * EDIM];
        }
        ob[(size_t)l * EDIM] = acc;
    }
}

extern "C" void kernel_launch(void* const* d_in, const int* in_sizes, int n_in,
                              void* d_out, int out_size, void* d_ws, size_t ws_size,
                              hipStream_t stream) {
    const float* q = (const float*)d_in[0];
    const float* k = (const float*)d_in[1];
    const float* v = (const float*)d_in[2];
    float* out = (float*)d_out;

    const size_t CORR_BYTES = (size_t)NB * EDIM * LEN * sizeof(float);  // 64 MB

    if (ws_size >= CORR_BYTES) {
        // Path A: qT in ws; kT staged in d_out (dead until topk rewrites it);
        // corr aliases qT.
        float* qT   = (float*)d_ws;
        float* kT   = (float*)d_out;
        float* corr = qT;
        transpose_qk<<<dim3(EDIM / 32, LEN / 32, NB), dim3(32, 8), 0, stream>>>(q, k, qT, kT);
        fft_corr<<<dim3(NB * EDIM / 2), dim3(256), 0, stream>>>(qT, kT, corr);
        topk_agg<<<dim3(LEN / 256, NB * NH), dim3(256), 0, stream>>>(corr, v, out, 0);
    } else {
        // Path B: chunk by heads; corr chunk lives in ws (512 KB per head).
        const size_t HEAD_BYTES = (size_t)HD * LEN * sizeof(float);
        int headsPer = (int)(ws_size / HEAD_BYTES);
        if (headsPer < 1) headsPer = 1;
        if (headsPer > NB * NH) headsPer = NB * NH;
        float* corr = (float*)d_ws;
        for (int hs = 0; hs < NB * NH; hs += headsPer) {
            int hc = NB * NH - hs < headsPer ? NB * NH - hs : headsPer;
            fft_corr_strided<<<dim3(hc * HD / 2), dim3(256), 0, stream>>>(q, k, corr, hs * HD);
            topk_agg<<<dim3(LEN / 256, hc), dim3(256), 0, stream>>>(corr, v, out, hs);
        }
    }
}

// Round 2
// 341.973 us; speedup vs baseline: 2.0318x; 1.2341x over previous
//
#include <hip/hip_runtime.h>
#include <math.h>

#define LEN   2048
#define EDIM  512
#define NB    16
#define NH    8
#define HD    64
#define TOPK  7
#define LDSN  (LEN + (LEN >> 5))   // 2112 float2: +1 pad per 32 kills bank conflicts

__device__ inline float2 cmul(float2 a, float2 b) {
    return make_float2(a.x * b.x - a.y * b.y, a.x * b.y + a.y * b.x);
}
__device__ inline float2 cadd(float2 a, float2 b) { return make_float2(a.x + b.x, a.y + b.y); }
__device__ inline float2 csub(float2 a, float2 b) { return make_float2(a.x - b.x, a.y - b.y); }
__device__ inline int pidx(int i) { return i + (i >> 5); }

// K0: (B, L, E) -> (B*E, L) transpose for q and k. 32x32 tiles.
__global__ __launch_bounds__(256) void transpose_qk(const float* __restrict__ q,
                                                    const float* __restrict__ k,
                                                    float* __restrict__ qT,
                                                    float* __restrict__ kT) {
    __shared__ float tile[32][33];
    int b  = blockIdx.z;
    int e0 = blockIdx.x * 32;
    int t0 = blockIdx.y * 32;
    const float* qb = q + (size_t)b * LEN * EDIM;
    const float* kb = k + (size_t)b * LEN * EDIM;
    float* qTb = qT + (size_t)b * EDIM * LEN;
    float* kTb = kT + (size_t)b * EDIM * LEN;
    int x = threadIdx.x;   // 0..31
    int y = threadIdx.y;   // 0..7
    for (int r = 0; r < 32; r += 8)
        tile[y + r][x] = qb[(size_t)(t0 + y + r) * EDIM + e0 + x];
    __syncthreads();
    for (int r = 0; r < 32; r += 8)
        qTb[(size_t)(e0 + y + r) * LEN + t0 + x] = tile[x][y + r];
    __syncthreads();
    for (int r = 0; r < 32; r += 8)
        tile[y + r][x] = kb[(size_t)(t0 + y + r) * EDIM + e0 + x];
    __syncthreads();
    for (int r = 0; r < 32; r += 8)
        kTb[(size_t)(e0 + y + r) * LEN + t0 + x] = tile[x][y + r];
}

// w^p for p=1..7, w = e^{i*ang}. One sincosf + squared chains (low error growth).
__device__ inline void tw8(float ang, float2* w) {
    float s, c;
    sincosf(ang, &s, &c);
    w[1] = make_float2(c, s);
    w[2] = cmul(w[1], w[1]);
    w[3] = cmul(w[2], w[1]);
    w[4] = cmul(w[2], w[2]);
    w[5] = cmul(w[3], w[2]);
    w[6] = cmul(w[3], w[3]);
    w[7] = cmul(w[4], w[3]);
}

// Forward radix-8 DIF pass: X_p = DFT8(x_r), store X_p * w_M^{q p} at base+stride*p.
// (w8 = e^{-2pi i/8}); w[] = powers of e^{-2pi i q/M}.
__device__ inline void fwd8(float2* P, int base, int stride, const float2* w) {
    const float C = 0.70710678118654752f;
    float2 v[8];
    #pragma unroll
    for (int r = 0; r < 8; ++r) v[r] = P[pidx(base + stride * r)];
    float2 y0 = cadd(v[0], v[4]), y1 = cadd(v[1], v[5]);
    float2 y2 = cadd(v[2], v[6]), y3 = cadd(v[3], v[7]);
    float2 t0 = csub(v[0], v[4]), t1 = csub(v[1], v[5]);
    float2 t2 = csub(v[2], v[6]), t3 = csub(v[3], v[7]);
    float2 z0 = t0;
    float2 z1 = make_float2(C * (t1.x + t1.y), C * (t1.y - t1.x));   // t1 * (C,-C)
    float2 z2 = make_float2(t2.y, -t2.x);                            // t2 * (0,-1)
    float2 z3 = make_float2(C * (t3.y - t3.x), -C * (t3.x + t3.y));  // t3 * (-C,-C)
    float2 a0 = cadd(y0, y2), a1 = cadd(y1, y3);
    float2 b0 = csub(y0, y2), tb = csub(y1, y3);
    float2 b1 = make_float2(tb.y, -tb.x);
    float2 c0 = cadd(z0, z2), c1 = cadd(z1, z3);
    float2 d0 = csub(z0, z2), td = csub(z1, z3);
    float2 d1 = make_float2(td.y, -td.x);
    float2 X0 = cadd(a0, a1), X4 = csub(a0, a1);
    float2 X2 = cadd(b0, b1), X6 = csub(b0, b1);
    float2 X1 = cadd(c0, c1), X5 = csub(c0, c1);
    float2 X3 = cadd(d0, d1), X7 = csub(d0, d1);
    P[pidx(base)]              = X0;
    P[pidx(base + stride)]     = cmul(X1, w[1]);
    P[pidx(base + 2 * stride)] = cmul(X2, w[2]);
    P[pidx(base + 3 * stride)] = cmul(X3, w[3]);
    P[pidx(base + 4 * stride)] = cmul(X4, w[4]);
    P[pidx(base + 5 * stride)] = cmul(X5, w[5]);
    P[pidx(base + 6 * stride)] = cmul(X6, w[6]);
    P[pidx(base + 7 * stride)] = cmul(X7, w[7]);
}

// Inverse radix-8 DIT pass: u_p = y_p * conj(w_M^{qp}) (w[] built from +ang),
// x_r = sum_p u_p w8+^{pr}, store at base+stride*r.
__device__ inline void inv8(float2* P, int base, int stride, const float2* w) {
    const float C = 0.70710678118654752f;
    float2 v[8];
    #pragma unroll
    for (int p = 0; p < 8; ++p) v[p] = P[pidx(base + stride * p)];
    #pragma unroll
    for (int p = 1; p < 8; ++p) v[p] = cmul(v[p], w[p]);
    float2 y0 = cadd(v[0], v[4]), y1 = cadd(v[1], v[5]);
    float2 y2 = cadd(v[2], v[6]), y3 = cadd(v[3], v[7]);
    float2 t0 = csub(v[0], v[4]), t1 = csub(v[1], v[5]);
    float2 t2 = csub(v[2], v[6]), t3 = csub(v[3], v[7]);
    float2 z0 = t0;
    float2 z1 = make_float2(C * (t1.x - t1.y), C * (t1.x + t1.y));   // t1 * (C, C)
    float2 z2 = make_float2(-t2.y, t2.x);                            // t2 * (0, 1)
    float2 z3 = make_float2(-C * (t3.x + t3.y), C * (t3.x - t3.y));  // t3 * (-C, C)
    float2 a0 = cadd(y0, y2), a1 = cadd(y1, y3);
    float2 b0 = csub(y0, y2), tb = csub(y1, y3);
    float2 b1 = make_float2(-tb.y, tb.x);
    float2 c0 = cadd(z0, z2), c1 = cadd(z1, z3);
    float2 d0 = csub(z0, z2), td = csub(z1, z3);
    float2 d1 = make_float2(-td.y, td.x);
    float2 X0 = cadd(a0, a1), X4 = csub(a0, a1);
    float2 X2 = cadd(b0, b1), X6 = csub(b0, b1);
    float2 X1 = cadd(c0, c1), X5 = csub(c0, c1);
    float2 X3 = cadd(d0, d1), X7 = csub(d0, d1);
    P[pidx(base)]              = X0;
    P[pidx(base + stride)]     = X1;
    P[pidx(base + 2 * stride)] = X2;
    P[pidx(base + 3 * stride)] = X3;
    P[pidx(base + 4 * stride)] = X4;
    P[pidx(base + 5 * stride)] = X5;
    P[pidx(base + 6 * stride)] = X6;
    P[pidx(base + 7 * stride)] = X7;
}

// Radix-4, no twiddle (q=0). Contiguous 4-blocks.
__device__ inline void fwd4(float2* P, int base) {
    int ib = pidx(base);           // base%32 <= 28, block of 4 never straddles pad
    float2 v0 = P[ib], v1 = P[ib + 1], v2 = P[ib + 2], v3 = P[ib + 3];
    float2 a0 = cadd(v0, v2), a1 = cadd(v1, v3);
    float2 b0 = csub(v0, v2), t = csub(v1, v3);
    float2 b1 = make_float2(t.y, -t.x);
    P[ib]     = cadd(a0, a1);
    P[ib + 2] = csub(a0, a1);
    P[ib + 1] = cadd(b0, b1);
    P[ib + 3] = csub(b0, b1);
}
__device__ inline void inv4(float2* P, int base) {
    int ib = pidx(base);
    float2 v0 = P[ib], v1 = P[ib + 1], v2 = P[ib + 2], v3 = P[ib + 3];
    float2 a0 = cadd(v0, v2), a1 = cadd(v1, v3);
    float2 b0 = csub(v0, v2), t = csub(v1, v3);
    float2 b1 = make_float2(-t.y, t.x);
    P[ib]     = cadd(a0, a1);
    P[ib + 2] = csub(a0, a1);
    P[ib + 1] = cadd(b0, b1);
    P[ib + 3] = csub(b0, b1);
}

// Storage slot of frequency k after DIF passes radix 8,8,8,4 (digit-reversed).
__device__ inline int slotOf(int k) {
    return ((k & 7) << 8) | (((k >> 3) & 7) << 5) | (((k >> 6) & 7) << 2) | ((k >> 9) & 3);
}

// Packed FFT correlation core (radix-8 register FFT, 4 passes/direction).
// In:  A = q0 + i*k0, Bs = q1 + i*k1 (time domain, padded layout).
// Out: A[t] = (corr0[t], corr1[t]) * LEN.
__device__ inline void fft_core(float2* A, float2* Bs, int tid) {
    const float PI2 = 6.283185307179586f;
    float2 w[8];
    // ---- forward: M = 2048, 256, 32, then radix-4
    tw8(-PI2 * (float)tid * (1.0f / 2048.0f), w);
    fwd8(A, tid, 256, w);
    fwd8(Bs, tid, 256, w);
    __syncthreads();
    {
        int c = tid >> 5, q = tid & 31, base = c * 256 + q;
        tw8(-PI2 * (float)q * (1.0f / 256.0f), w);
        fwd8(A, base, 32, w);
        fwd8(Bs, base, 32, w);
    }
    __syncthreads();
    {
        int c = tid >> 2, q = tid & 3, base = c * 32 + q;
        tw8(-PI2 * (float)q * (1.0f / 32.0f), w);
        fwd8(A, base, 4, w);
        fwd8(Bs, base, 4, w);
    }
    __syncthreads();
    fwd4(A, 4 * tid);  fwd4(A, 4 * (tid + 256));
    fwd4(Bs, 4 * tid); fwd4(Bs, 4 * (tid + 256));
    __syncthreads();
    // ---- pointwise in digit-reversed domain: Hermitian unpack of packed
    // real pair, C = Q*conj(K) per channel, repack W = C0 + i*C1.
    for (int f = tid; f <= 1024; f += 256) {
        int nf = (2048 - f) & 2047;
        int ia = pidx(slotOf(f));
        int ib = pidx(slotOf(nf));
        float2 z1 = A[ia],  z1n = A[ib];
        float2 z2 = Bs[ia], z2n = Bs[ib];
        float Qx = 0.5f * (z1.x + z1n.x), Qy = 0.5f * (z1.y - z1n.y);
        float Kx = 0.5f * (z1.y + z1n.y), Ky = 0.5f * (z1n.x - z1.x);
        float C1x = Qx * Kx + Qy * Ky;
        float C1y = Qy * Kx - Qx * Ky;
        float Px = 0.5f * (z2.x + z2n.x), Py = 0.5f * (z2.y - z2n.y);
        float Lx = 0.5f * (z2.y + z2n.y), Ly = 0.5f * (z2n.x - z2.x);
        float C2x = Px * Lx + Py * Ly;
        float C2y = Py * Lx - Px * Ly;
        A[ia] = make_float2(C1x - C2y, C1y + C2x);
        if (f != 0 && f != 1024)
            A[ib] = make_float2(C1x + C2y, C2x - C1y);
    }
    __syncthreads();
    // ---- inverse (A only), mirrored pass order, conj twiddles
    inv4(A, 4 * tid); inv4(A, 4 * (tid + 256));
    __syncthreads();
    {
        int c = tid >> 2, q = tid & 3, base = c * 32 + q;
        tw8(PI2 * (float)q * (1.0f / 32.0f), w);
        inv8(A, base, 4, w);
    }
    __syncthreads();
    {
        int c = tid >> 5, q = tid & 31, base = c * 256 + q;
        tw8(PI2 * (float)q * (1.0f / 256.0f), w);
        inv8(A, base, 32, w);
    }
    __syncthreads();
    tw8(PI2 * (float)tid * (1.0f / 2048.0f), w);
    inv8(A, tid, 256, w);
    __syncthreads();
}

// K1 (Path A): two contiguous channel rows per block (from transposed bufs).
// corr may alias qT: rows ch0,ch0+1 fully read into LDS before the store.
__global__ __launch_bounds__(256) void fft_corr(const float* qT,
                                                const float* kT,
                                                float* corr) {
    __shared__ float2 A[LDSN];
    __shared__ float2 Bs[LDSN];
    int ch0 = blockIdx.x * 2;
    int tid = threadIdx.x;
    const float4* q4 = (const float4*)(qT + (size_t)ch0 * LEN);
    const float4* k4 = (const float4*)(kT + (size_t)ch0 * LEN);
    for (int t4 = tid; t4 < LEN / 4; t4 += 256) {
        float4 qa = q4[t4],           ka = k4[t4];
        float4 qb = q4[t4 + LEN / 4], kb = k4[t4 + LEN / 4];
        int t  = t4 * 4;
        int ib = t + (t >> 5);
        A[ib]      = make_float2(qa.x, ka.x);
        A[ib + 1]  = make_float2(qa.y, ka.y);
        A[ib + 2]  = make_float2(qa.z, ka.z);
        A[ib + 3]  = make_float2(qa.w, ka.w);
        Bs[ib]     = make_float2(qb.x, kb.x);
        Bs[ib + 1] = make_float2(qb.y, kb.y);
        Bs[ib + 2] = make_float2(qb.z, kb.z);
        Bs[ib + 3] = make_float2(qb.w, kb.w);
    }
    __syncthreads();
    fft_core(A, Bs, tid);
    const float inv = 1.0f / (float)LEN;
    float4* c0 = (float4*)(corr + (size_t)ch0 * LEN);
    float4* c1 = (float4*)(corr + (size_t)(ch0 + 1) * LEN);
    for (int t4 = tid; t4 < LEN / 4; t4 += 256) {
        int t  = t4 * 4;
        int ib = t + (t >> 5);
        c0[t4] = make_float4(A[ib].x * inv, A[ib + 1].x * inv,
                             A[ib + 2].x * inv, A[ib + 3].x * inv);
        c1[t4] = make_float4(A[ib].y * inv, A[ib + 1].y * inv,
                             A[ib + 2].y * inv, A[ib + 3].y * inv);
    }
}

// K1 (Path B): read q,k strided directly from (B,L,E); corr rows chunk-local.
__global__ __launch_bounds__(256) void fft_corr_strided(const float* q,
                                                        const float* k,
                                                        float* corr,
                                                        int chStart) {
    __shared__ float2 A[LDSN];
    __shared__ float2 Bs[LDSN];
    int chLocal = blockIdx.x * 2;
    int gch = chStart + chLocal;
    int b   = gch >> 9;           // / EDIM
    int e   = gch & (EDIM - 1);   // even (HD per head, paired)
    int tid = threadIdx.x;
    const float* qr = q + (size_t)b * LEN * EDIM + e;
    const float* kr = k + (size_t)b * LEN * EDIM + e;
    for (int t = tid; t < LEN; t += 256) {
        float2 qv = *(const float2*)(qr + (size_t)t * EDIM);
        float2 kv = *(const float2*)(kr + (size_t)t * EDIM);
        int ib = t + (t >> 5);
        A[ib]  = make_float2(qv.x, kv.x);
        Bs[ib] = make_float2(qv.y, kv.y);
    }
    __syncthreads();
    fft_core(A, Bs, tid);
    const float inv = 1.0f / (float)LEN;
    float4* c0 = (float4*)(corr + (size_t)chLocal * LEN);
    float4* c1 = (float4*)(corr + (size_t)(chLocal + 1) * LEN);
    for (int t4 = tid; t4 < LEN / 4; t4 += 256) {
        int t  = t4 * 4;
        int ib = t + (t >> 5);
        c0[t4] = make_float4(A[ib].x * inv, A[ib + 1].x * inv,
                             A[ib + 2].x * inv, A[ib + 3].x * inv);
        c1[t4] = make_float4(A[ib].y * inv, A[ib + 1].y * inv,
                             A[ib + 2].y * inv, A[ib + 3].y * inv);
    }
}

// K2: per (b,h,l): top-7 over 64 channel-scores, softmax, gather-weighted sum.
// Phase 1: one thread per l, branchless 7-deep insertion network.
// Phase 2: lane <-> channel; coalesced 256B value gathers (mostly L2-hits).
__global__ __launch_bounds__(256) void topk_agg(const float* __restrict__ corr,
                                                const float* __restrict__ values,
                                                float* __restrict__ out,
                                                int bhBase) {
    __shared__ float2 w_d[256][TOPK];   // (weight, bitcast delay) per local l
    int l0 = blockIdx.x * 256;
    int lh = blockIdx.y;            // local head index within chunk
    int bh = bhBase + lh;
    int b  = bh >> 3;
    int h  = bh & 7;
    int tid = threadIdx.x;

    const float* cb = corr + (size_t)lh * HD * LEN + l0 + tid;
    float wk[TOPK];
    int   dk[TOPK];
    #pragma unroll
    for (int t = 0; t < TOPK; ++t) { wk[t] = -INFINITY; dk[t] = 0; }
    #pragma unroll 8
    for (int c = 0; c < HD; ++c) {
        float nv = cb[(size_t)c * LEN];
        int   nd = c;
        #pragma unroll
        for (int t = 0; t < TOPK; ++t) {   // stable: strict > keeps low index first
            bool  m  = nv > wk[t];
            float tv = wk[t]; int td = dk[t];
            wk[t] = m ? nv : tv;
            dk[t] = m ? nd : td;
            nv    = m ? tv : nv;
            nd    = m ? td : nd;
        }
    }
    float mx = wk[0], sum = 0.f;
    float e[TOPK];
    #pragma unroll
    for (int t = 0; t < TOPK; ++t) { e[t] = expf(wk[t] - mx); sum += e[t]; }
    float invs = 1.f / sum;
    #pragma unroll
    for (int t = 0; t < TOPK; ++t)
        w_d[tid][t] = make_float2(e[t] * invs, __int_as_float(dk[t]));
    __syncthreads();

    int lane = tid & 63;
    int wave = tid >> 6;
    const float* vb = values + (size_t)b * LEN * EDIM + h * HD + lane;
    float*       ob = out    + (size_t)b * LEN * EDIM + h * HD + lane;
    for (int i = 0; i < 64; ++i) {
        int lp = wave * 64 + i;
        int l  = l0 + lp;
        float acc = 0.f;
        #pragma unroll
        for (int t = 0; t < TOPK; ++t) {
            float2 wd = w_d[lp][t];     // wave-uniform -> LDS broadcast
            int idx = (l - __float_as_int(wd.y)) & (LEN - 1);
            acc += wd.x * vb[(size_t)idx * EDIM];
        }
        ob[(size_t)l * EDIM] = acc;
    }
}

extern "C" void kernel_launch(void* const* d_in, const int* in_sizes, int n_in,
                              void* d_out, int out_size, void* d_ws, size_t ws_size,
                              hipStream_t stream) {
    const float* q = (const float*)d_in[0];
    const float* k = (const float*)d_in[1];
    const float* v = (const float*)d_in[2];
    float* out = (float*)d_out;

    const size_t CORR_BYTES = (size_t)NB * EDIM * LEN * sizeof(float);  // 64 MB

    if (ws_size >= CORR_BYTES) {
        // Path A: qT in ws; kT staged in d_out (dead until topk rewrites it);
        // corr aliases qT.
        float* qT   = (float*)d_ws;
        float* kT   = (float*)d_out;
        float* corr = qT;
        transpose_qk<<<dim3(EDIM / 32, LEN / 32, NB), dim3(32, 8), 0, stream>>>(q, k, qT, kT);
        fft_corr<<<dim3(NB * EDIM / 2), dim3(256), 0, stream>>>(qT, kT, corr);
        topk_agg<<<dim3(LEN / 256, NB * NH), dim3(256), 0, stream>>>(corr, v, out, 0);
    } else {
        // Path B: chunk by heads; corr chunk lives in ws (512 KB per head).
        const size_t HEAD_BYTES = (size_t)HD * LEN * sizeof(float);
        int headsPer = (int)(ws_size / HEAD_BYTES);
        if (headsPer < 1) headsPer = 1;
        if (headsPer > NB * NH) headsPer = NB * NH;
        float* corr = (float*)d_ws;
        for (int hs = 0; hs < NB * NH; hs += headsPer) {
            int hc = NB * NH - hs < headsPer ? NB * NH - hs : headsPer;
            fft_corr_strided<<<dim3(hc * HD / 2), dim3(256), 0, stream>>>(q, k, corr, hs * HD);
            topk_agg<<<dim3(LEN / 256, hc), dim3(256), 0, stream>>>(corr, v, out, hs);
        }
    }
}